// Round 12
// baseline (114.590 us; speedup 1.0000x reference)
//
#include <hip/hip_runtime.h>
#include <stdint.h>

#define IN_F   4096
#define OUT_F  768
#define NB     8
#define BATCH  4096
#define WCOLS  (OUT_F*NB)   // 6144
#define PREDN  (BATCH*OUT_F) // 3145728

typedef short  bf16x8  __attribute__((ext_vector_type(8)));
typedef float  f32x4   __attribute__((ext_vector_type(4)));
typedef float  f32x2   __attribute__((ext_vector_type(2)));
typedef unsigned short ushort4v __attribute__((ext_vector_type(4)));

__device__ __forceinline__ unsigned short f2bf(float f){
    union { float f; uint32_t u; } v; v.f = f;
    uint32_t u = v.u;
    u += 0x7FFFu + ((u >> 16) & 1u);   // round-to-nearest-even
    return (unsigned short)(u >> 16);
}

__device__ __forceinline__ void gload16(const void* g, void* l){
    __builtin_amdgcn_global_load_lds(
        (const __attribute__((address_space(1))) unsigned int*)g,
        (__attribute__((address_space(3))) unsigned int*)l, 16, 0, 0);
}

#define SBAR() __builtin_amdgcn_sched_barrier(0)

__device__ __forceinline__ float sig8dot(const f32x4 a, const f32x4 b, float& pol){
    float s0 = __builtin_amdgcn_rcpf(1.f + __expf(-a[0]));
    float s1 = __builtin_amdgcn_rcpf(1.f + __expf(-a[1]));
    float s2 = __builtin_amdgcn_rcpf(1.f + __expf(-a[2]));
    float s3 = __builtin_amdgcn_rcpf(1.f + __expf(-a[3]));
    float s4 = __builtin_amdgcn_rcpf(1.f + __expf(-b[0]));
    float s5 = __builtin_amdgcn_rcpf(1.f + __expf(-b[1]));
    float s6 = __builtin_amdgcn_rcpf(1.f + __expf(-b[2]));
    float s7 = __builtin_amdgcn_rcpf(1.f + __expf(-b[3]));
    pol += s0*(1.f-s0) + s1*(1.f-s1) + s2*(1.f-s2) + s3*(1.f-s3)
         + s4*(1.f-s4) + s5*(1.f-s5) + s6*(1.f-s6) + s7*(1.f-s7);
    return s0 + 2.f*s1 + 4.f*s2 + 8.f*s3
         + 16.f*s4 + 32.f*s5 + 64.f*s6 - 128.f*s7;
}

// ------- kernel 1a: weight decode, fill-shaped (4 elems/thread) -------------
// grid (128, 24): tile 32k x 32n. Thread: 2k x 2n elements, 8 dense f4 loads.
__launch_bounds__(256)
__global__ void decode_weight(const float* __restrict__ w,
                              unsigned short* __restrict__ bt,
                              float* __restrict__ polp){
    __shared__ unsigned short tile[32][34];   // [n][k], +2 pad
    __shared__ float part[4];
    const int tid = threadIdx.x;
    const int k0 = blockIdx.x * 32;
    const int n0 = blockIdx.y * 32;
    const int kl = (tid >> 4) * 2;            // 0..30 even
    const int nq = (tid & 15) * 2;            // 0..30 even
    const f32x4* wf4 = (const f32x4*)w;

    // 8 dense f4 loads: rows k0+kl, k0+kl+1; 16 consecutive floats each
    f32x4 r0a, r0b, r0c, r0d, r1a, r1b, r1c, r1d;
    {
        size_t b0 = (size_t)(k0 + kl)     * 1536 + (size_t)(n0 + nq) * 2;
        size_t b1 = (size_t)(k0 + kl + 1) * 1536 + (size_t)(n0 + nq) * 2;
        r0a = wf4[b0];   r0b = wf4[b0+1]; r0c = wf4[b0+2]; r0d = wf4[b0+3];
        r1a = wf4[b1];   r1b = wf4[b1+1]; r1c = wf4[b1+2]; r1d = wf4[b1+3];
    }
    SBAR();
    float pol = 0.f;
    tile[nq  ][kl  ] = f2bf(sig8dot(r0a, r0b, pol));
    tile[nq+1][kl  ] = f2bf(sig8dot(r0c, r0d, pol));
    tile[nq  ][kl+1] = f2bf(sig8dot(r1a, r1b, pol));
    tile[nq+1][kl+1] = f2bf(sig8dot(r1c, r1d, pol));

    #pragma unroll
    for (int off = 32; off; off >>= 1) pol += __shfl_down(pol, off);
    if ((tid & 63) == 0) part[tid >> 6] = pol;
    __syncthreads();
    // write transposed: 32 n-rows x 64B (full-line) via 128 threads
    if (tid < 128){
        const int n  = tid >> 2;
        const int dw = tid & 3;           // 4 x 16B per row
        uint4 v;
        v.x = *(const unsigned int*)&tile[n][dw*8];
        v.y = *(const unsigned int*)&tile[n][dw*8+2];
        v.z = *(const unsigned int*)&tile[n][dw*8+4];
        v.w = *(const unsigned int*)&tile[n][dw*8+6];
        *(uint4*)(bt + (size_t)(n0+n)*IN_F + k0 + dw*8) = v;
    }
    if (tid == 0)
        polp[blockIdx.y * 128 + blockIdx.x] = part[0]+part[1]+part[2]+part[3];
}

// ------- kernel 1b: latent f32 -> bf16, fill-shaped (4 f4/thread) -----------
__launch_bounds__(256)
__global__ void latent_cast(const float* __restrict__ lat,
                            unsigned short* __restrict__ abf){
    const int tid  = threadIdx.x;
    const int base = blockIdx.x * 4096;      // floats
    const f32x4* p = (const f32x4*)(lat + base);
    ushort4v* o = (ushort4v*)(abf + base);
    f32x4 v[4];
    #pragma unroll
    for (int i = 0; i < 4; ++i) v[i] = p[tid + i*256];
    SBAR();
    #pragma unroll
    for (int i = 0; i < 4; ++i){
        ushort4v u;
        u[0]=f2bf(v[i][0]); u[1]=f2bf(v[i][1]);
        u[2]=f2bf(v[i][2]); u[3]=f2bf(v[i][3]);
        o[tid + i*256] = u;
    }
}

// ------- kernel 2: bf16 GEMM, 128x96 tile, K-split x2, m97 loop -------------
#define BM 128
#define BN 96
#define BK 64
#define NTH 32                     // K-steps per half (K=2048)
#define ABYTES (BM*BK*2)           // 16384
#define BBYTES (BN*BK*2)           // 12288
#define BUFB   (ABYTES+BBYTES)     // 28672

__launch_bounds__(256)
__global__ void gemm_pred(const unsigned short* __restrict__ abf,
                          const unsigned short* __restrict__ bt,
                          float* __restrict__ pred){
    __shared__ __align__(16) char smem[2*BUFB];   // 56 KB -> 2 blocks/CU
    const int tid = threadIdx.x;
    const int w   = tid >> 6;
    const int l   = tid & 63;
    const int s   = l & 15, g = l >> 4;
    const int wr  = w >> 1, wc = w & 1;    // 2x2 waves, wave tile 64x48
    const int bid  = blockIdx.x;
    const int half = bid >> 8;             // K-half
    const int rem  = bid & 255;
    const int m0   = (rem >> 3) * BM;
    const int n0   = (rem & 7)  * BN;      // bid&7 == n-panel -> XCD-stable
    const int kb   = half * (NTH*BK);

    f32x4 accv[4][3];
    #pragma unroll
    for (int m = 0; m < 4; ++m)
        #pragma unroll
        for (int n = 0; n < 3; ++n)
            accv[m][n] = (f32x4){0.f,0.f,0.f,0.f};

    const int c8  = tid & 7;
    const int r0  = tid >> 3;                    // 0..31; (r0+32i)&7 == r0&7
    const int scw = ((c8 ^ (r0 & 7)) << 3);
    const unsigned short* aS = abf + (size_t)(m0 + r0) * IN_F + kb + scw;
    const unsigned short* bS = bt  + (size_t)(n0 + r0) * IN_F + kb + scw;

    #define STAGE(kt, base) do {                                           \
        const int _ko = (kt) * BK;                                         \
        char* _ad = (base) + tid*16;                                       \
        char* _bd = (base) + ABYTES + tid*16;                              \
        _Pragma("unroll")                                                  \
        for (int _i = 0; _i < 4; ++_i)                                     \
            gload16(aS + (size_t)_i*32*IN_F + _ko, _ad + _i*4096);         \
        _Pragma("unroll")                                                  \
        for (int _i = 0; _i < 3; ++_i)                                     \
            gload16(bS + (size_t)_i*32*IN_F + _ko, _bd + _i*4096);         \
    } while (0)

    #define COMPUTE(base) do {                                             \
        char* _Ab = (base);                                                \
        char* _Bb = (base) + ABYTES;                                       \
        _Pragma("unroll")                                                  \
        for (int _kk = 0; _kk < 2; ++_kk){                                 \
            bf16x8 _af[4], _bf[3];                                         \
            _Pragma("unroll")                                              \
            for (int _m = 0; _m < 4; ++_m){                                \
                int _r  = wr*64 + _m*16 + s;                               \
                int _ch = _r*8 + ((_kk*4 + g) ^ (_r & 7));                 \
                _af[_m] = *(const bf16x8*)(_Ab + _ch*16);                  \
            }                                                              \
            _Pragma("unroll")                                              \
            for (int _n = 0; _n < 3; ++_n){                                \
                int _r  = wc*48 + _n*16 + s;                               \
                int _ch = _r*8 + ((_kk*4 + g) ^ (_r & 7));                 \
                _bf[_n] = *(const bf16x8*)(_Bb + _ch*16);                  \
            }                                                              \
            __builtin_amdgcn_s_setprio(1);                                 \
            _Pragma("unroll")                                              \
            for (int _m = 0; _m < 4; ++_m)                                 \
                _Pragma("unroll")                                          \
                for (int _n = 0; _n < 3; ++_n)                             \
                    accv[_m][_n] = __builtin_amdgcn_mfma_f32_16x16x32_bf16(\
                        _af[_m], _bf[_n], accv[_m][_n], 0, 0, 0);          \
            __builtin_amdgcn_s_setprio(0);                                 \
        }                                                                  \
    } while (0)

    char* b0 = smem;
    char* b1 = smem + BUFB;
    STAGE(0, b0);
    __syncthreads();
    for (int t = 0; t < NTH; ++t){
        if (t + 1 < NTH) STAGE(t + 1, (t & 1) ? b0 : b1);
        COMPUTE((t & 1) ? b1 : b0);
        __syncthreads();
    }

    float* slab = pred + (size_t)half * PREDN;
    #pragma unroll
    for (int m = 0; m < 4; ++m){
        int rbase = m0 + wr*64 + m*16 + g*4;
        #pragma unroll
        for (int n = 0; n < 3; ++n){
            int col = n0 + wc*48 + n*16 + s;
            #pragma unroll
            for (int jj = 0; jj < 4; ++jj)
                slab[(size_t)(rbase+jj)*OUT_F + col] = accv[m][n][jj];
        }
    }
}

// ------- kernel 3: loss pass, fill-shaped (2 elems/thread) ------------------
__launch_bounds__(256)
__global__ void loss_pass(const float* __restrict__ pred,
                          const float* __restrict__ ts,
                          float* __restrict__ lossp){
    __shared__ float part[4];
    const int tid = threadIdx.x;
    const int e0  = (blockIdx.x * 256 + tid) * 2;
    const f32x4* tsp = (const f32x4*)(ts + (size_t)e0 * 8);
    f32x4 t0 = tsp[0], t1 = tsp[1], t2 = tsp[2], t3 = tsp[3];
    f32x2 p0 = *(const f32x2*)(pred + e0);
    f32x2 p1 = *(const f32x2*)(pred + (size_t)PREDN + e0);
    SBAR();
    float is0 = t0[0] + 2.f*t0[1] + 4.f*t0[2] + 8.f*t0[3]
              + 16.f*t1[0] + 32.f*t1[1] + 64.f*t1[2] - 128.f*t1[3];
    float is1 = t2[0] + 2.f*t2[1] + 4.f*t2[2] + 8.f*t2[3]
              + 16.f*t3[0] + 32.f*t3[1] + 64.f*t3[2] - 128.f*t3[3];
    float d0 = (p0[0] + p1[0]) - is0;
    float d1 = (p0[1] + p1[1]) - is1;
    float local = d0*d0 + d1*d1;
    #pragma unroll
    for (int off = 32; off; off >>= 1) local += __shfl_down(local, off);
    if ((tid & 63) == 0) part[tid >> 6] = local;
    __syncthreads();
    if (tid == 0) lossp[blockIdx.x] = part[0]+part[1]+part[2]+part[3];
}

// ------- kernel 4: finalize -------------------------------------------------
__launch_bounds__(256)
__global__ void finalize(const float* __restrict__ lossp,
                         const float* __restrict__ polp,
                         float* __restrict__ out){
    __shared__ float sm[2][4];
    const int tid = threadIdx.x;
    float a = 0.f, b = 0.f;
    for (int i = tid; i < 6144; i += 256) a += lossp[i];
    for (int i = tid; i < 3072; i += 256) b += polp[i];
    #pragma unroll
    for (int off = 32; off; off >>= 1){
        a += __shfl_down(a, off);
        b += __shfl_down(b, off);
    }
    if ((tid & 63) == 0){ sm[0][tid >> 6] = a; sm[1][tid >> 6] = b; }
    __syncthreads();
    if (tid == 0){
        float sa = sm[0][0]+sm[0][1]+sm[0][2]+sm[0][3];
        float sb = sm[1][0]+sm[1][1]+sm[1][2]+sm[1][3];
        out[0] = sa * (1.0f / ((float)BATCH * (float)OUT_F * 128.0f));
        out[1] = sb * (1.0f / ((float)IN_F * (float)WCOLS));
    }
}

extern "C" void kernel_launch(void* const* d_in, const int* in_sizes, int n_in,
                              void* d_out, int out_size, void* d_ws, size_t ws_size,
                              hipStream_t stream){
    const float* latent   = (const float*)d_in[0];
    const float* true_sum = (const float*)d_in[1];
    const float* weight   = (const float*)d_in[2];
    char* ws = (char*)d_ws;
    float* lossp = (float*)ws;                                  // 24 KB
    float* polp  = (float*)(ws + 32768);                        // 12 KB
    unsigned short* bt  = (unsigned short*)(ws + 65536);        // 6 MB
    unsigned short* abf = (unsigned short*)(ws + 65536 + 6291456);      // 32 MB
    float* pred = (float*)(ws + 65536 + 6291456 + 33554432);    // 2x12.6 MB
    float* out = (float*)d_out;

    decode_weight<<<dim3(IN_F/32, OUT_F/32), 256, 0, stream>>>(weight, bt, polp);
    latent_cast<<<(BATCH*IN_F)/4096, 256, 0, stream>>>(latent, abf);
    gemm_pred<<<512, 256, 0, stream>>>(abf, bt, pred);
    loss_pass<<<PREDN/512, 256, 0, stream>>>(pred, true_sum, lossp);
    finalize<<<1, 256, 0, stream>>>(lossp, polp, out);
}